// Round 1
// baseline (266.337 us; speedup 1.0000x reference)
//
#include <hip/hip_runtime.h>

// Problem dims
#define NB 32
#define NA 64
#define SLEN 256
#define NH 128
#define RLEN 64
#define NE 16

typedef _Float16 f16;
typedef _Float16 f16x8 __attribute__((ext_vector_type(8)));
typedef float f32x4 __attribute__((ext_vector_type(4)));

// ---------------------------------------------------------------------------
// K0: pack re_w1[:64,:] (64x128) and re_w2 (128x256) into fp16 MFMA B-fragment
// order: packed[((kt*NT+nt)*64 + lane)*8 + t] = W[kt*32 + (lane>>4)*8 + t][nt*16 + (lane&15)]
// ---------------------------------------------------------------------------
__global__ __launch_bounds__(256) void k0_pack(const float* __restrict__ re_w1,
                                               const float* __restrict__ re_w2,
                                               f16* __restrict__ pw1,
                                               f16* __restrict__ pw2) {
  int idx = blockIdx.x * 256 + threadIdx.x;
  if (idx < 8192) {  // re_w1a: K=64 (KT=2), N=128 (NT=8)
    int t = idx & 7, l = (idx >> 3) & 63, rem = idx >> 9;
    int nt = rem & 7, kt = rem >> 3;
    int k = kt * 32 + (l >> 4) * 8 + t;
    int n = nt * 16 + (l & 15);
    pw1[idx] = (f16)re_w1[k * NH + n];
  } else {
    int i2 = idx - 8192;  // re_w2: K=128 (KT=4), N=256 (NT=16)
    if (i2 < 32768) {
      int t = i2 & 7, l = (i2 >> 3) & 63, rem = i2 >> 9;
      int nt = rem & 15, kt = rem >> 4;
      int k = kt * 32 + (l >> 4) * 8 + t;
      int n = nt * 16 + (l & 15);
      pw2[i2] = (f16)re_w2[k * 256 + n];
    }
  }
}

// ---------------------------------------------------------------------------
// K1: s = mlp2(states); sproj1 = s @ re_w1[64:192] + re_b1.  One row per block.
// ---------------------------------------------------------------------------
__global__ __launch_bounds__(128) void k1_s(const float* __restrict__ states,
                                            const float* __restrict__ se_w1,
                                            const float* __restrict__ se_b1,
                                            const float* __restrict__ se_w2,
                                            const float* __restrict__ se_b2,
                                            const float* __restrict__ re_w1,
                                            const float* __restrict__ re_b1,
                                            float* __restrict__ s_out,
                                            float* __restrict__ sproj1) {
  __shared__ float x[SLEN];
  __shared__ float t[NH];
  const int row = blockIdx.x;
  const int h = threadIdx.x;
  const float* xr = states + (size_t)row * SLEN;
  x[h] = xr[h];
  x[h + 128] = xr[h + 128];
  __syncthreads();
  float acc = se_b1[h];
#pragma unroll 4
  for (int k = 0; k < SLEN; ++k) acc += x[k] * se_w1[k * NH + h];
  t[h] = fmaxf(acc, 0.f);
  __syncthreads();
  float a2 = se_b2[h];
#pragma unroll 4
  for (int k = 0; k < NH; ++k) a2 += t[k] * se_w2[k * NH + h];
  float sv = fmaxf(a2, 0.f);
  s_out[(size_t)row * NH + h] = sv;
  x[h] = sv;  // reuse x[0:128] as s row (layer1 reads of x finished before 2nd barrier)
  __syncthreads();
  float a3 = re_b1[h];
#pragma unroll 4
  for (int k = 0; k < NH; ++k) a3 += x[k] * re_w1[(64 + k) * NH + h];
  sproj1[(size_t)row * NH + h] = a3;
}

// ---------------------------------------------------------------------------
// K3: dominant kernel. One block per (b,i). 256 threads = 4 waves.
//   t[64x128] = relu(relations[b,i] @ re_w1[:64] + sproj1[b,:])     (MFMA)
//   r[64x256] = relu(t @ re_w2 + re_b2)                             (MFMA)
//   r_red[b,i,0:128]  = sum_j r*alive[j]   (waves 0,1)
//   r_red[b,i,128:256]= max_j r*alive[j]   (waves 2,3)
//   if i==agent_id: r_agent[b,j,:] = r (fp16)
// ---------------------------------------------------------------------------
__global__ __launch_bounds__(256) void k3_rel(const float* __restrict__ relations,
                                              const float* __restrict__ alive_mask,
                                              const float* __restrict__ sproj1,
                                              const float* __restrict__ re_b2,
                                              const f16* __restrict__ pw1,
                                              const f16* __restrict__ pw2,
                                              const int* __restrict__ agent_id,
                                              float* __restrict__ r_red,
                                              f16* __restrict__ r_agent) {
  __shared__ f16 tl[64 * 128];
  __shared__ float alive[NA];
  const int bid = blockIdx.x;
  const int b = bid >> 6, i = bid & 63;
  const int tid = threadIdx.x;
  const int w = tid >> 6, l = tid & 63;
  const int lr = l & 15, lh = l >> 4;
  if (tid < 64) alive[tid] = alive_mask[b * NA + tid];

  // ---- layer 1 ----
  const float* relp = relations + (size_t)bid * NA * RLEN;
  f16x8 a1[4][2];
#pragma unroll
  for (int mt = 0; mt < 4; ++mt)
#pragma unroll
    for (int kt = 0; kt < 2; ++kt) {
      const float* p = relp + (mt * 16 + lr) * RLEN + kt * 32 + lh * 8;
      float4 v0 = *(const float4*)p;
      float4 v1 = *(const float4*)(p + 4);
      f16x8 a;
      a[0] = (f16)v0.x; a[1] = (f16)v0.y; a[2] = (f16)v0.z; a[3] = (f16)v0.w;
      a[4] = (f16)v1.x; a[5] = (f16)v1.y; a[6] = (f16)v1.z; a[7] = (f16)v1.w;
      a1[mt][kt] = a;
    }
  f16x8 b1f[2][2];
#pragma unroll
  for (int kt = 0; kt < 2; ++kt)
#pragma unroll
    for (int ntl = 0; ntl < 2; ++ntl)
      b1f[kt][ntl] = *(const f16x8*)(pw1 + ((size_t)(kt * 8 + w * 2 + ntl) * 64 + l) * 8);
  f32x4 acc1[4][2];
#pragma unroll
  for (int mt = 0; mt < 4; ++mt)
#pragma unroll
    for (int ntl = 0; ntl < 2; ++ntl) acc1[mt][ntl] = (f32x4){0.f, 0.f, 0.f, 0.f};
#pragma unroll
  for (int kt = 0; kt < 2; ++kt)
#pragma unroll
    for (int mt = 0; mt < 4; ++mt)
#pragma unroll
      for (int ntl = 0; ntl < 2; ++ntl)
        acc1[mt][ntl] = __builtin_amdgcn_mfma_f32_16x16x32_f16(a1[mt][kt], b1f[kt][ntl],
                                                               acc1[mt][ntl], 0, 0, 0);
  // add sproj1 (has re_b1 folded in), relu, store fp16 into swizzled LDS
  const float* sp = sproj1 + (size_t)b * NA * NH;
#pragma unroll
  for (int mt = 0; mt < 4; ++mt)
#pragma unroll
    for (int ntl = 0; ntl < 2; ++ntl) {
      int h = w * 32 + ntl * 16 + lr;
#pragma unroll
      for (int reg = 0; reg < 4; ++reg) {
        int j = mt * 16 + lh * 4 + reg;
        float v = acc1[mt][ntl][reg] + sp[j * NH + h];
        v = fmaxf(v, 0.f);
        unsigned off = (unsigned)((j * NH + h) * 2) ^ ((unsigned)(j & 7) << 4);
        *(f16*)((char*)tl + off) = (f16)v;
      }
    }
  __syncthreads();

  // ---- layer 2 ----  wave w owns output cols [w*64, w*64+64)
  f32x4 acc2[4][4];
#pragma unroll
  for (int mt = 0; mt < 4; ++mt)
#pragma unroll
    for (int ntl = 0; ntl < 4; ++ntl) acc2[mt][ntl] = (f32x4){0.f, 0.f, 0.f, 0.f};
#pragma unroll
  for (int kt2 = 0; kt2 < 4; ++kt2) {
    f16x8 a2[4];
#pragma unroll
    for (int mt = 0; mt < 4; ++mt) {
      int row = mt * 16 + lr;
      unsigned off = (unsigned)(row * 256 + kt2 * 64 + lh * 16) ^ ((unsigned)(row & 7) << 4);
      a2[mt] = *(const f16x8*)((char*)tl + off);
    }
    f16x8 b2f[4];
#pragma unroll
    for (int ntl = 0; ntl < 4; ++ntl)
      b2f[ntl] = *(const f16x8*)(pw2 + ((size_t)(kt2 * 16 + w * 4 + ntl) * 64 + l) * 8);
#pragma unroll
    for (int mt = 0; mt < 4; ++mt)
#pragma unroll
      for (int ntl = 0; ntl < 4; ++ntl)
        acc2[mt][ntl] = __builtin_amdgcn_mfma_f32_16x16x32_f16(a2[mt], b2f[ntl],
                                                               acc2[mt][ntl], 0, 0, 0);
  }

  // ---- epilogue: bias+relu, masked sum/max over j, agent slice store ----
  const int aid = agent_id[0];
  const bool isagent = (i == aid);
  const bool domax = (w >= 2);  // waves 2,3 hold cols 128..255 => max half
  float red[4];
#pragma unroll
  for (int ntl = 0; ntl < 4; ++ntl) red[ntl] = 0.f;
#pragma unroll
  for (int ntl = 0; ntl < 4; ++ntl) {
    int n = w * 64 + ntl * 16 + lr;
    float bias = re_b2[n];
#pragma unroll
    for (int mt = 0; mt < 4; ++mt)
#pragma unroll
      for (int reg = 0; reg < 4; ++reg) {
        int j = mt * 16 + lh * 4 + reg;
        float rv = fmaxf(acc2[mt][ntl][reg] + bias, 0.f);
        float rm = rv * alive[j];
        red[ntl] = domax ? fmaxf(red[ntl], rm) : (red[ntl] + rm);
        if (isagent) r_agent[((size_t)b * NA + j) * 256 + n] = (f16)rv;
      }
  }
#pragma unroll
  for (int ntl = 0; ntl < 4; ++ntl) {
    float v = red[ntl];
    float v1 = __shfl_xor(v, 16, 64);
    v = domax ? fmaxf(v, v1) : v + v1;
    float v2 = __shfl_xor(v, 32, 64);
    v = domax ? fmaxf(v, v2) : v + v2;
    if (lh == 0) r_red[(size_t)bid * 256 + w * 64 + ntl * 16 + lr] = v;
  }
}

// ---------------------------------------------------------------------------
// K4: s_new = relu([s, r_avr, r_max] @ ra_w + ra_b);
//     sproj2 = s_new @ ae_w1[256:384]; sproj3 = s_new @ ae_w1[384:512]
// ---------------------------------------------------------------------------
__global__ __launch_bounds__(128) void k4_snew(const float* __restrict__ s,
                                               const float* __restrict__ r_red,
                                               const float* __restrict__ ra_w,
                                               const float* __restrict__ ra_b,
                                               const float* __restrict__ ae_w1,
                                               float* __restrict__ s_new,
                                               float* __restrict__ sproj2,
                                               float* __restrict__ sproj3) {
  __shared__ float in3[384];
  __shared__ float t[NH];
  const int row = blockIdx.x;
  const int h = threadIdx.x;
  in3[h] = s[(size_t)row * NH + h];
  in3[128 + h] = r_red[(size_t)row * 256 + h] * (1.f / 64.f);
  in3[256 + h] = r_red[(size_t)row * 256 + 128 + h];
  __syncthreads();
  float acc = ra_b[h];
#pragma unroll 4
  for (int k = 0; k < 384; ++k) acc += in3[k] * ra_w[k * NH + h];
  float sv = fmaxf(acc, 0.f);
  s_new[(size_t)row * NH + h] = sv;
  t[h] = sv;
  __syncthreads();
  float a2 = 0.f, a3 = 0.f;
#pragma unroll 4
  for (int k = 0; k < NH; ++k) {
    float tv = t[k];
    a2 += tv * ae_w1[(256 + k) * NH + h];
    a3 += tv * ae_w1[(384 + k) * NH + h];
  }
  sproj2[(size_t)row * NH + h] = a2;
  sproj3[(size_t)row * NH + h] = a3;
}

// ---------------------------------------------------------------------------
// K5a: per b, compute sel row (action_embed row or ae-MLP of row jj=action-E)
// and the passive row. One block per b.
// ---------------------------------------------------------------------------
__global__ __launch_bounds__(128) void k5a_sel(const float* __restrict__ ae_w1,
                                               const float* __restrict__ ae_b1,
                                               const float* __restrict__ ae_w2,
                                               const float* __restrict__ ae_b2,
                                               const float* __restrict__ action_embed,
                                               const int* __restrict__ action,
                                               const int* __restrict__ agent_id,
                                               const f16* __restrict__ r_agent,
                                               const float* __restrict__ sproj2,
                                               const float* __restrict__ sproj3,
                                               float* __restrict__ sel_ws,
                                               float* __restrict__ passive_ws,
                                               float* __restrict__ out_sel) {
  __shared__ float rr[256];
  __shared__ float t[NH];
  const int b = blockIdx.x;
  const int h = threadIdx.x;
  const int act = action[b];
  const int aid = agent_id[0];
  if (act < NE) {
    float sv = action_embed[act * NH + h];
    sel_ws[b * NH + h] = sv;
    out_sel[b * NH + h] = sv;
    passive_ws[b * NH + h] = 0.f;
    return;
  }
  const int jj = act - NE;
  const int row = b * NA + jj;
  const int arow = b * NA + aid;
  rr[h] = (float)r_agent[(size_t)row * 256 + h];
  rr[128 + h] = (float)r_agent[(size_t)row * 256 + 128 + h];
  __syncthreads();
  float acc = ae_b1[h] + sproj2[(size_t)row * NH + h] + sproj3[(size_t)arow * NH + h];
#pragma unroll 4
  for (int k = 0; k < 256; ++k) acc += rr[k] * ae_w1[k * NH + h];
  float u = fmaxf(acc, 0.f);
  t[h] = u;
  __syncthreads();
  float a_act = ae_b2[h], a_pas = ae_b2[128 + h];
#pragma unroll 4
  for (int k = 0; k < NH; ++k) {
    float tv = t[k];
    a_act += tv * ae_w2[k * 256 + h];
    a_pas += tv * ae_w2[k * 256 + 128 + h];
  }
  a_act = fmaxf(a_act, 0.f);
  a_pas = fmaxf(a_pas, 0.f);
  sel_ws[b * NH + h] = a_act;
  out_sel[b * NH + h] = a_act;
  passive_ws[b * NH + h] = a_pas;
}

// ---------------------------------------------------------------------------
// K5b: assemble state and passive_sel outputs.
// ---------------------------------------------------------------------------
__global__ __launch_bounds__(256) void k5b_out(const float* __restrict__ s_new,
                                               const float* __restrict__ sel_ws,
                                               const float* __restrict__ passive_ws,
                                               const int* __restrict__ action,
                                               const int* __restrict__ agent_id,
                                               float* __restrict__ out_state,
                                               float* __restrict__ out_passive) {
  int idx = blockIdx.x * 256 + threadIdx.x;
  if (idx >= NB * NA * NH) return;
  int h = idx & 127;
  int row = idx >> 7;
  int b = row >> 6, i = row & 63;
  int act = action[b];
  int aid = agent_id[0];
  float st = s_new[idx];
  float ps = 0.f;
  if (act >= NE && i == act - NE) ps = passive_ws[b * NH + h];
  st += ps;
  if (i == aid) st += sel_ws[b * NH + h];
  out_state[idx] = st;
  out_passive[idx] = ps;
}

// ---------------------------------------------------------------------------
extern "C" void kernel_launch(void* const* d_in, const int* in_sizes, int n_in,
                              void* d_out, int out_size, void* d_ws, size_t ws_size,
                              hipStream_t stream) {
  (void)in_sizes; (void)n_in; (void)out_size; (void)ws_size;
  const float* states       = (const float*)d_in[0];
  const float* relations    = (const float*)d_in[1];
  const float* alive_mask   = (const float*)d_in[2];
  const float* se_w1        = (const float*)d_in[3];
  const float* se_b1        = (const float*)d_in[4];
  const float* se_w2        = (const float*)d_in[5];
  const float* se_b2        = (const float*)d_in[6];
  const float* re_w1        = (const float*)d_in[7];
  const float* re_b1        = (const float*)d_in[8];
  const float* re_w2        = (const float*)d_in[9];
  const float* re_b2        = (const float*)d_in[10];
  const float* ra_w         = (const float*)d_in[11];
  const float* ra_b         = (const float*)d_in[12];
  const float* ae_w1        = (const float*)d_in[13];
  const float* ae_b1        = (const float*)d_in[14];
  const float* ae_w2        = (const float*)d_in[15];
  const float* ae_b2        = (const float*)d_in[16];
  const float* action_embed = (const float*)d_in[17];
  const int*   action       = (const int*)d_in[19];
  const int*   agent_id     = (const int*)d_in[20];
  float* out = (float*)d_out;

  // workspace layout (float elements)
  float* wsf       = (float*)d_ws;
  float* s         = wsf;                // 2048*128
  float* sproj1    = wsf + 262144;       // 2048*128
  float* r_red     = wsf + 524288;       // 2048*256 (sum | max)
  float* s_new     = wsf + 1048576;      // 2048*128
  float* sproj2    = wsf + 1310720;      // 2048*128
  float* sproj3    = wsf + 1572864;      // 2048*128
  float* sel_ws    = wsf + 1835008;      // 32*128
  float* passive_ws= wsf + 1839104;      // 32*128
  f16*   wsh       = (f16*)(wsf + 1843200);
  f16*   r_agent   = wsh;                // 32*64*256 fp16
  f16*   pw1       = wsh + 524288;       // 8192 fp16
  f16*   pw2       = wsh + 532480;       // 32768 fp16

  k0_pack<<<160, 256, 0, stream>>>(re_w1, re_w2, pw1, pw2);
  k1_s<<<2048, 128, 0, stream>>>(states, se_w1, se_b1, se_w2, se_b2, re_w1, re_b1, s, sproj1);
  k3_rel<<<2048, 256, 0, stream>>>(relations, alive_mask, sproj1, re_b2, pw1, pw2,
                                   agent_id, r_red, r_agent);
  k4_snew<<<2048, 128, 0, stream>>>(s, r_red, ra_w, ra_b, ae_w1, s_new, sproj2, sproj3);
  k5a_sel<<<32, 128, 0, stream>>>(ae_w1, ae_b1, ae_w2, ae_b2, action_embed, action,
                                  agent_id, r_agent, sproj2, sproj3, sel_ws, passive_ws,
                                  out + 262144);
  k5b_out<<<1024, 256, 0, stream>>>(s_new, sel_ws, passive_ws, action, agent_id,
                                    out, out + 266240);
}